// Round 11
// baseline (55.072 us; speedup 1.0000x reference)
//
#include <hip/hip_runtime.h>
#include <hip/hip_bf16.h>
#include <math.h>

#define B_   4
#define C_   128
#define H_   96
#define W_   192
#define HW_  (H_*W_)
#define NPIX (B_*HW_)

typedef __attribute__((ext_vector_type(8))) short bf16x8;
typedef __attribute__((ext_vector_type(4))) float f32x4;

__device__ __forceinline__ unsigned f2bfu(float f) {
    __hip_bfloat16 h = __float2bfloat16(f);     // pairs fuse to v_cvt_pk_bf16_f32
    return (unsigned)*(unsigned short*)&h;
}
__device__ __forceinline__ float bflo(unsigned u) { return __uint_as_float(u << 16); }
__device__ __forceinline__ float bfhi(unsigned u) { return __uint_as_float(u & 0xFFFF0000u); }

__device__ __forceinline__ bf16x8 pack8(const float* v) {
    int4 q;
    q.x = (int)(f2bfu(v[0]) | (f2bfu(v[1]) << 16));
    q.y = (int)(f2bfu(v[2]) | (f2bfu(v[3]) << 16));
    q.z = (int)(f2bfu(v[4]) | (f2bfu(v[5]) << 16));
    q.w = (int)(f2bfu(v[6]) | (f2bfu(v[7]) << 16));
    return *(bf16x8*)&q;
}

__device__ __forceinline__ float dot8u(const float* r, uint4 fv) {
    return r[0]*bflo(fv.x) + r[1]*bfhi(fv.x)
         + r[2]*bflo(fv.y) + r[3]*bfhi(fv.y)
         + r[4]*bflo(fv.z) + r[5]*bfhi(fv.z)
         + r[6]*bflo(fv.w) + r[7]*bfhi(fv.w);
}

// ---------------------------------------------------------------------------
// prep: blocks 0..7 compute Mc = Wk^T Wq rows rb*16..+15, written directly in
// bf16 MFMA A-fragment order. block 8: u2 = Wk^T bq, v2 = Wq^T bk, c0 = bq.bk
// ---------------------------------------------------------------------------
__global__ __launch_bounds__(256) void prep_kernel(
    const float* __restrict__ Wq, const float* __restrict__ Wk,
    const float* __restrict__ bq, const float* __restrict__ bk,
    short* __restrict__ Apack, float* __restrict__ u2,
    float* __restrict__ v2, float* __restrict__ c0)
{
    if (blockIdx.x < 8) {
        const int rb   = blockIdx.x;
        const int t    = threadIdx.x;
        const int lane = t & 63;
        const int row  = rb * 16 + (lane & 15);
        const int colb = (t >> 6) * 32 + (lane >> 4) * 8;
        float a[8];
#pragma unroll
        for (int j = 0; j < 8; ++j) a[j] = 0.f;
#pragma unroll 1
        for (int c = 0; c < C_; c += 8) {
            float  wk[8];
            float4 w0[8], w1[8];
#pragma unroll
            for (int u = 0; u < 8; ++u) {
                wk[u] = Wk[(c + u) * C_ + row];
                w0[u] = *(const float4*)(Wq + (c + u) * C_ + colb);
                w1[u] = *(const float4*)(Wq + (c + u) * C_ + colb + 4);
            }
#pragma unroll
            for (int u = 0; u < 8; ++u) {
                a[0] = fmaf(wk[u], w0[u].x, a[0]); a[1] = fmaf(wk[u], w0[u].y, a[1]);
                a[2] = fmaf(wk[u], w0[u].z, a[2]); a[3] = fmaf(wk[u], w0[u].w, a[3]);
                a[4] = fmaf(wk[u], w1[u].x, a[4]); a[5] = fmaf(wk[u], w1[u].y, a[5]);
                a[6] = fmaf(wk[u], w1[u].z, a[6]); a[7] = fmaf(wk[u], w1[u].w, a[7]);
            }
        }
        bf16x8 v = pack8(a);
        *(bf16x8*)(Apack + ((size_t)rb * 256 + t) * 8) = v;
    } else {
        const int t = threadIdx.x;
        if (t < 128) {
            float a = 0.f;
            for (int c = 0; c < C_; ++c) a = fmaf(Wk[c * C_ + t], bq[c], a);
            u2[t] = a;
        } else {
            const int i = t - 128;
            float a = 0.f;
            for (int c = 0; c < C_; ++c) a = fmaf(Wq[c * C_ + i], bk[c], a);
            v2[i] = a;
        }
        if (t == 0) {
            float a = 0.f;
            for (int c = 0; c < C_; ++c) a = fmaf(bq[c], bk[c], a);
            c0[0] = a;
        }
    }
}

// ---------------------------------------------------------------------------
// prepass: wave-autonomous (no LDS, no barrier). Wave = 16 consecutive px.
// Loads f (coalesced), converts to bf16 once, writes fbf (NHWC bf16, full-line
// coalesced), computes R = Mc f + u2 via 32 MFMA, writes rbf (NHWC bf16) and
// bet[px] = v2.f + c0.
// ---------------------------------------------------------------------------
__global__ __launch_bounds__(256) void prepass_kernel(
    const float* __restrict__ f, const short* __restrict__ Apack,
    const float* __restrict__ u2v, const float* __restrict__ v2v,
    const float* __restrict__ c0p,
    unsigned short* __restrict__ fbf, unsigned short* __restrict__ rbf,
    float* __restrict__ bet)
{
    const int t    = threadIdx.x;
    const int lane = t & 63;
    const int w    = t >> 6;
    const int g    = lane >> 4, p = lane & 15;

    const int wg  = blockIdx.x;                   // 1152 = 8*144
    const int idx = (wg & 7) * 144 + (wg >> 3);   // XCD-band swizzle (bijective)
    const int p0  = idx * 64 + w * 16;            // wave's 16-px base (same row)
    const int b   = p0 / HW_;
    const int sp  = p0 % HW_;
    const float* fb = f + (size_t)b * C_ * HW_;
    const size_t pxf = (size_t)b * HW_ + sp + p;  // this lane's pixel (global)

    // ---- load + convert this lane's pixel, all 128 ch (fully coalesced) ----
    bf16x8 fC[4];
#pragma unroll
    for (int ks = 0; ks < 4; ++ks) {
        const float* src = fb + (size_t)(ks * 32 + g * 8) * HW_ + sp + p;
        float v[8];
#pragma unroll
        for (int j = 0; j < 8; ++j) v[j] = src[(size_t)j * HW_];
        fC[ks] = pack8(v);
    }

    // ---- write fbf (16B/lane, consecutive lanes -> full 64B lines) ----
#pragma unroll
    for (int ks = 0; ks < 4; ++ks)
        *(uint4*)(fbf + pxf * 128 + ks * 32 + g * 8) = *(const uint4*)&fC[ks];

    // ---- beta = v2 . f_p (+c0), butterfly over g-groups ----
    float bl = 0.f;
#pragma unroll
    for (int ks = 0; ks < 4; ++ks) {
        const float* vv = v2v + ks * 32 + g * 8;
        const uint4 qd = *(const uint4*)&fC[ks];
        bl += bflo(qd.x) * vv[0] + bfhi(qd.x) * vv[1]
            + bflo(qd.y) * vv[2] + bfhi(qd.y) * vv[3]
            + bflo(qd.z) * vv[4] + bfhi(qd.z) * vv[5]
            + bflo(qd.w) * vv[6] + bfhi(qd.w) * vv[7];
    }
    bl += __shfl_xor(bl, 16, 64);
    bl += __shfl_xor(bl, 32, 64);
    if (g == 0) bet[pxf] = bl + *c0p;

    // ---- R-GEMM: 128 out-ch x 16 px ----
    f32x4 acc[8];
#pragma unroll
    for (int rb = 0; rb < 8; ++rb) acc[rb] = (f32x4){0.f, 0.f, 0.f, 0.f};
#pragma unroll
    for (int ks = 0; ks < 4; ++ks) {
#pragma unroll
        for (int rb = 0; rb < 8; ++rb) {
            const bf16x8 afr = *(const bf16x8*)(Apack +
                ((size_t)((rb * 4 + ks) * 64 + lane)) * 8);
            acc[rb] = __builtin_amdgcn_mfma_f32_16x16x32_bf16(afr, fC[ks], acc[rb], 0, 0, 0);
        }
    }

    // ---- +u2, pack, write rbf (C-frag: lane holds ch rb*16+g*4+i, px p) ----
#pragma unroll
    for (int rb = 0; rb < 8; ++rb) {
        const f32x4 uu = *(const f32x4*)(u2v + rb * 16 + g * 4);
        const f32x4 vv = acc[rb] + uu;
        uint2 pk;
        pk.x = f2bfu(vv[0]) | (f2bfu(vv[1]) << 16);
        pk.y = f2bfu(vv[2]) | (f2bfu(vv[3]) << 16);
        *(uint2*)(rbf + pxf * 128 + rb * 16 + g * 4) = pk;
    }
}

// ---------------------------------------------------------------------------
// attn: no LDS, no MFMA, no barrier. Thread = (px, 1/4-ch slice); 4 thr/px.
// Slice owns channels {(q*4+slice)*8 .. +8} for q=0..3 -> every uint4 load
// instruction covers full 64B lines (consecutive lanes = consecutive 16B).
// 8x8 px tiles keep the 3x3 halo (10x10x256B = 26KB) L1-resident.
// s[9] butterflied over the 4 slice lanes; slices 0,1 do PV for v=0,1.
// ---------------------------------------------------------------------------
__global__ __launch_bounds__(256) void attn_kernel(
    const unsigned short* __restrict__ fbf, const unsigned short* __restrict__ rbf,
    const float* __restrict__ bet, const float* __restrict__ flow,
    float* __restrict__ out)
{
    const int t     = threadIdx.x;
    const int slice = t & 3;
    const int pxl   = t >> 2;                    // 0..63
    const int pxx   = pxl & 7, pyy = pxl >> 3;

    const int wg  = blockIdx.x;                  // 1152 = 8*144
    const int idx = (wg & 7) * 144 + (wg >> 3);  // XCD-band swizzle
    const int b   = idx / 288;
    const int rem = idx - b * 288;
    const int ty  = rem / 24, tx = rem - ty * 24;
    const int gy  = ty * 8 + pyy, gx = tx * 8 + pxx;
    const int sp  = gy * W_ + gx;
    const size_t base = (size_t)b * HW_;

    // ---- r slice: channels (q*4+slice)*8+j, unpacked to fp32 ----
    float rf[32];
#pragma unroll
    for (int q = 0; q < 4; ++q) {
        const uint4 rv = *(const uint4*)(rbf + (base + sp) * 128 + q * 32 + slice * 8);
        rf[q*8+0] = bflo(rv.x); rf[q*8+1] = bfhi(rv.x);
        rf[q*8+2] = bflo(rv.y); rf[q*8+3] = bfhi(rv.y);
        rf[q*8+4] = bflo(rv.z); rf[q*8+5] = bfhi(rv.z);
        rf[q*8+6] = bflo(rv.w); rf[q*8+7] = bfhi(rv.w);
    }
    const float beta = bet[base + sp];

    int   spn[9];
    float mk[9];
#pragma unroll
    for (int n = 0; n < 9; ++n) {
        const int yn = gy + n / 3 - 1, xn = gx + n % 3 - 1;
        const bool ok = (yn >= 0) && (yn < H_) && (xn >= 0) && (xn < W_);
        mk[n]  = ok ? 1.f : 0.f;
        spn[n] = ok ? yn * W_ + xn : sp;
    }

    // ---- 9 window dots over this slice's 32 channels ----
    float s[9];
#pragma unroll
    for (int n = 0; n < 9; ++n) {
        const unsigned short* fp = fbf + (base + spn[n]) * 128;
        float a = 0.f;
#pragma unroll
        for (int q = 0; q < 4; ++q) {
            const uint4 fv = *(const uint4*)(fp + q * 32 + slice * 8);
            a += dot8u(&rf[q * 8], fv);
        }
        s[n] = a;
    }

    // ---- butterfly over the 4 slice lanes (full s on every lane) ----
#pragma unroll
    for (int n = 0; n < 9; ++n) {
        s[n] += __shfl_xor(s[n], 1, 64);
        s[n] += __shfl_xor(s[n], 2, 64);
    }

    // ---- softmax + PV (slices 0,1 -> v=0,1) ----
    const float scale = 0.08838834764831845f;    // 1/sqrt(128)
    float sv[9], e[9];
    float m = -1e30f;
#pragma unroll
    for (int n = 0; n < 9; ++n) {
        sv[n] = (mk[n] != 0.f) ? (s[n] + beta) * scale : 0.f;
        m = fmaxf(m, sv[n]);
    }
    float sum = 0.f;
#pragma unroll
    for (int n = 0; n < 9; ++n) { e[n] = __expf(sv[n] - m); sum += e[n]; }
    const float inv = 1.f / sum;

    if (slice < 2) {
        const float* f0 = flow + ((size_t)b * 2 + slice) * HW_;
        float o = 0.f;
#pragma unroll
        for (int n = 0; n < 9; ++n) o += e[n] * mk[n] * f0[spn[n]];
        out[((size_t)b * 2 + slice) * HW_ + sp] = o * inv;
    }
}

extern "C" void kernel_launch(void* const* d_in, const int* in_sizes, int n_in,
                              void* d_out, int out_size, void* d_ws, size_t ws_size,
                              hipStream_t stream) {
    const float* f   = (const float*)d_in[0];
    const float* flw = (const float*)d_in[1];
    const float* Wq  = (const float*)d_in[2];
    const float* bq  = (const float*)d_in[3];
    const float* Wk  = (const float*)d_in[4];
    const float* bk  = (const float*)d_in[5];
    float* out = (float*)d_out;

    short* Apack = (short*)d_ws;                  // 32 KB
    float* u2    = (float*)(Apack + 128 * 128);   // 512 B
    float* v2    = u2 + 128;                      // 512 B
    float* c0    = v2 + 128;                      // 4 B
    unsigned short* fbf = (unsigned short*)((char*)d_ws + (1u << 20));   // 18.9 MB
    unsigned short* rbf = fbf + (size_t)NPIX * C_;                       // 18.9 MB
    float*          bet = (float*)(rbf + (size_t)NPIX * C_);             // 0.3 MB

    prep_kernel<<<9, 256, 0, stream>>>(Wq, Wk, bq, bk, Apack, u2, v2, c0);
    prepass_kernel<<<1152, 256, 0, stream>>>(f, Apack, u2, v2, c0, fbf, rbf, bet);
    attn_kernel<<<1152, 256, 0, stream>>>(fbf, rbf, bet, flw, out);
}